// Round 1
// 2394.647 us; speedup vs baseline: 1.4487x; 1.4487x over previous
//
#include <hip/hip_runtime.h>
#include <math.h>

namespace {
constexpr int kB = 512;
constexpr int kT = 256;
constexpr int kD = 256;
constexpr int kS = 8;
constexpr int kStRow = 292;  // 288 data (physk layout) + 4; keeps q-chunks on distinct bank quads
constexpr int kRedRow = 12;  // reduction table row stride (8 wave slots + pad)

__device__ __forceinline__ int physk(int k) { return k + ((k >> 5) << 2); }
}

// ---------------------------------------------------------------------------
// Kernel A: XW[b,t,:] = inputs[b,t,:] @ W, skipping t >= lengths[b]. (unchanged)
// ---------------------------------------------------------------------------
__global__ __launch_bounds__(256, 2)
void xw_gemm_kernel(const float* __restrict__ X, const float* __restrict__ W,
                    const int* __restrict__ lengths, float* __restrict__ XW) {
  const int m0 = blockIdx.x * 32;
  const int b = m0 >> 8;
  const int t0 = m0 & 255;
  if (t0 >= lengths[b]) return;

  __shared__ float Xs[32][kD];
  const int tid = threadIdx.x;
  const int j  = tid & 63;
  const int rg = tid >> 6;

  const float4* Xg4 = (const float4*)(X + (size_t)m0 * kD);
  float4* Xs4 = (float4*)&Xs[0][0];
  for (int i = tid; i < 32 * kD / 4; i += 256) Xs4[i] = Xg4[i];
  __syncthreads();

  float4 acc[8];
#pragma unroll
  for (int i = 0; i < 8; ++i) acc[i] = make_float4(0.f, 0.f, 0.f, 0.f);

  const float4* W4 = (const float4*)W;
  const float4* Xrow = (const float4*)&Xs[rg * 8][0];

  for (int k4 = 0; k4 < kD / 4; ++k4) {
    float4 w0 = W4[(size_t)(4 * k4 + 0) * 64 + j];
    float4 w1 = W4[(size_t)(4 * k4 + 1) * 64 + j];
    float4 w2 = W4[(size_t)(4 * k4 + 2) * 64 + j];
    float4 w3 = W4[(size_t)(4 * k4 + 3) * 64 + j];
#pragma unroll
    for (int i = 0; i < 8; ++i) {
      float4 x = Xrow[i * 64 + k4];
      acc[i].x = fmaf(x.x, w0.x, fmaf(x.y, w1.x, fmaf(x.z, w2.x, fmaf(x.w, w3.x, acc[i].x))));
      acc[i].y = fmaf(x.x, w0.y, fmaf(x.y, w1.y, fmaf(x.z, w2.y, fmaf(x.w, w3.y, acc[i].y))));
      acc[i].z = fmaf(x.x, w0.z, fmaf(x.y, w1.z, fmaf(x.z, w2.z, fmaf(x.w, w3.z, acc[i].z))));
      acc[i].w = fmaf(x.x, w0.w, fmaf(x.y, w1.w, fmaf(x.z, w2.w, fmaf(x.w, w3.w, acc[i].w))));
    }
  }
  float4* XW4 = (float4*)XW;
#pragma unroll
  for (int i = 0; i < 8; ++i)
    XW4[(size_t)(m0 + rg * 8 + i) * 64 + j] = acc[i];
}

// ---------------------------------------------------------------------------
// Kernel B: GK[b,t,s] = inputs[b,t,:] . keys[s,:], t < lengths[b] only. (unchanged)
// ---------------------------------------------------------------------------
__global__ __launch_bounds__(256, 4)
void gk_kernel(const float* __restrict__ inputs, const float* __restrict__ keys,
               const int* __restrict__ lengths, float* __restrict__ GK) {
  const int b = blockIdx.x;
  const int tid = threadIdx.x;
  const int lane = tid & 63;
  const int wid = tid >> 6;
  const int len = lengths[b];

  __shared__ float4 Ks4[kS * 64];
  for (int i = tid; i < kS * 64; i += 256) Ks4[i] = ((const float4*)keys)[i];
  __syncthreads();

  const float4* X4 = (const float4*)inputs;
  for (int t = wid; t < len; t += 4) {
    float4 x = X4[((size_t)b * kT + t) * 64 + lane];
    float p[kS];
#pragma unroll
    for (int s = 0; s < kS; ++s) {
      float4 kk = Ks4[s * 64 + lane];
      p[s] = fmaf(x.x, kk.x, fmaf(x.y, kk.y, fmaf(x.z, kk.z, x.w * kk.w)));
    }
#pragma unroll
    for (int off = 32; off >= 1; off >>= 1) {
#pragma unroll
      for (int s = 0; s < kS; ++s) p[s] += __shfl_xor(p[s], off, 64);
    }
    if (lane == 0) {
      float* g = GK + ((size_t)b * kT + t) * kS;
#pragma unroll
      for (int s = 0; s < kS; ++s) g[s] = p[s];
    }
  }
}

// ---------------------------------------------------------------------------
// Kernel S: rank lengths descending (stable). order[r] = batch with rank r.
// O(512^2) counting rank in one block — trivial cost, graph-capture safe.
// ---------------------------------------------------------------------------
__global__ __launch_bounds__(512)
void sort_lengths_kernel(const int* __restrict__ lengths, int* __restrict__ order) {
  __shared__ int L[kB];
  const int i = threadIdx.x;
  L[i] = lengths[i];
  __syncthreads();
  const int li = L[i];
  int r = 0;
  for (int j = 0; j < kB; ++j) {
    const int lj = L[j];
    r += (lj > li || (lj == li && j < i)) ? 1 : 0;
  }
  order[r] = i;
}

// ---------------------------------------------------------------------------
// Kernel C (v4): recurrence. 256 blocks x 512 threads; each block owns TWO
// batches: bA = order[blk] (long), bB = order[511-blk] (short). T=512 means
// 8 waves -> 2 waves/SIMD -> 256-VGPR cap, so the per-thread U slice can be
// 4 cols x 32 k = 128 VGPR (vs 64 at T=1024). This HALVES the ds_read_b128
// state traffic per step (the measured bottleneck: ~2048 b128/step-pair
// ~ 25k cyc ~ the 12.5us/step). Fusing 2 batches shares the 3 barriers and
// lets the long batch run at single-batch cost once the short one is done
// (tail fix: OccupancyPercent showed ~half the dispatch was drain).
// Thread (w=tid>>6, jj=lane>>3, q=lane&7): col-group cg=w*8+jj (cols 4cg..+3),
// k-chunk [32q,32q+32). k-reduction: shfl_xor 1,2,4 (bit-identical tree to
// the previous kernel). Gate/norm: shfl_xor 8,16,32 + [8][12] LDS tables.
// Epilogue s-split by q (lane handles s=q).
// ---------------------------------------------------------------------------
__global__ __launch_bounds__(512, 2)
void dynmem_rec4_kernel(const float* __restrict__ inputs,   // [B,T,D]
                        const int*   __restrict__ lengths,  // [B]
                        const float* __restrict__ keys,     // [S,D]
                        const float* __restrict__ U,        // [D,D]
                        const float* __restrict__ V,        // [D,D]
                        const float* __restrict__ gate_bias,
                        const float* __restrict__ state_bias,
                        const float* __restrict__ XW,       // [B,T,D]
                        const float* __restrict__ GK,       // [B,T,S]
                        const int*   __restrict__ order,    // [B] desc by length
                        float* __restrict__ out)            // [B,S,D]
{
  const int blk = blockIdx.x;
  const int bA = order[blk];
  const int bB = order[kB - 1 - blk];
  const int tid = threadIdx.x;
  const int w = tid >> 6;        // 0..7
  const int lane = tid & 63;
  const int q = lane & 7;        // k-chunk AND the state s this lane finalizes
  const int jj = lane >> 3;      // 0..7
  const int cg = w * 8 + jj;     // col-group 0..63
  const int c0 = 4 * cg;
  const int c0p = physk(c0);     // 4 cols stay contiguous inside a 32-group

  __shared__ float StA[kS * kStRow];
  __shared__ float StB[kS * kStRow];
  __shared__ float KVL[kS * kD];
  __shared__ float redGA[kS * kRedRow], redGB[kS * kRedRow];
  __shared__ float redNA[kS * kRedRow], redNB[kS * kRedRow];

  // init both states = keys (padded layout)
  for (int i = tid; i < kS * kD; i += 512) {
    int s = i >> 8, dd = i & 255;
    float kv = keys[i];
    int pa = s * kStRow + physk(dd);
    StA[pa] = kv;
    StB[pa] = kv;
  }

  // persistent U slice: rows q*32..q*32+31, cols c0..c0+3 (128 VGPRs)
  float4 u4[32];
#pragma unroll
  for (int kk = 0; kk < 32; ++kk)
    u4[kk] = *(const float4*)(U + (size_t)(q * 32 + kk) * kD + c0);

  // KV[s][d] = (keys @ V)[s][d] + state_bias[d]; thread (h2,d) does 4 s rows.
  // keys[] accesses are wave-uniform -> scalar loads.
  {
    const int h2 = tid >> 8, d = tid & 255;   // h2 in {0,1}
    float a0 = 0.f, a1 = 0.f, a2 = 0.f, a3 = 0.f;
    const float* Vc = V + d;
    const float* K0 = keys + (size_t)(4 * h2 + 0) * kD;
    const float* K1 = keys + (size_t)(4 * h2 + 1) * kD;
    const float* K2 = keys + (size_t)(4 * h2 + 2) * kD;
    const float* K3 = keys + (size_t)(4 * h2 + 3) * kD;
    for (int k = 0; k < kD; ++k) {
      float v = Vc[(size_t)k * kD];
      a0 = fmaf(K0[k], v, a0);
      a1 = fmaf(K1[k], v, a1);
      a2 = fmaf(K2[k], v, a2);
      a3 = fmaf(K3[k], v, a3);
    }
    float sb = state_bias[d];
    KVL[(4 * h2 + 0) * kD + d] = a0 + sb;
    KVL[(4 * h2 + 1) * kD + d] = a1 + sb;
    KVL[(4 * h2 + 2) * kD + d] = a2 + sb;
    KVL[(4 * h2 + 3) * kD + d] = a3 + sb;
  }

  const float gb = gate_bias[0];
  int lenA = lengths[bA]; lenA = lenA < 0 ? 0 : (lenA > kT ? kT : lenA);
  int lenB = lengths[bB]; lenB = lenB < 0 ? 0 : (lenB > kT ? kT : lenB);
  const int lenM = lenA > lenB ? lenA : lenB;

  __syncthreads();  // states + KVL ready

  const float4 kvq = *(const float4*)(KVL + q * kD + c0);
  float4 srA = *(const float4*)(StA + q * kStRow + c0p);
  float4 srB = *(const float4*)(StB + q * kStRow + c0p);

  const float* SqA = StA + q * 36;  // physical base of k-chunk q within a row
  const float* SqB = StB + q * 36;

  for (int t = 0; t < lenM; ++t) {
    const bool dA = t < lenA;
    const bool dB = t < lenB;

    float4 xA4, xwA4, xB4, xwB4;
    float gkqA = 0.f, gkqB = 0.f;
    if (dA) {
      const size_t baseA = (size_t)bA * kT + t;
      xA4  = *(const float4*)(inputs + baseA * kD + c0);
      xwA4 = *(const float4*)(XW + baseA * kD + c0);
      gkqA = GK[baseA * kS + q];
    }
    if (dB) {
      const size_t baseB = (size_t)bB * kT + t;
      xB4  = *(const float4*)(inputs + baseB * kD + c0);
      xwB4 = *(const float4*)(XW + baseB * kD + c0);
      gkqB = GK[baseB * kS + q];
    }

    // ---- gate partials for s=q over own 4 state cols ----
    if (dA) {
      float pg = fmaf(xA4.x, srA.x, fmaf(xA4.y, srA.y, fmaf(xA4.z, srA.z, xA4.w * srA.w)));
      pg += __shfl_xor(pg, 8, 64);
      pg += __shfl_xor(pg, 16, 64);
      pg += __shfl_xor(pg, 32, 64);
      if (lane < 8) redGA[lane * kRedRow + w] = pg;
    }
    if (dB) {
      float pg = fmaf(xB4.x, srB.x, fmaf(xB4.y, srB.y, fmaf(xB4.z, srB.z, xB4.w * srB.w)));
      pg += __shfl_xor(pg, 8, 64);
      pg += __shfl_xor(pg, 16, 64);
      pg += __shfl_xor(pg, 32, 64);
      if (lane < 8) redGB[lane * kRedRow + w] = pg;
    }

    // ---- matmul A: C[s][4 cols] over k-chunk q (U in registers) ----
    float4 cA = make_float4(0.f, 0.f, 0.f, 0.f);
    if (dA) {
      float4 C[8];
#pragma unroll
      for (int s = 0; s < 8; ++s) C[s] = make_float4(0.f, 0.f, 0.f, 0.f);
#pragma unroll
      for (int k4 = 0; k4 < 8; ++k4) {
        const float4 u0 = u4[4 * k4 + 0], u1 = u4[4 * k4 + 1];
        const float4 u2 = u4[4 * k4 + 2], u3 = u4[4 * k4 + 3];
#pragma unroll
        for (int s = 0; s < 8; ++s) {
          float4 sv = *(const float4*)(SqA + s * kStRow + 4 * k4);
          C[s].x = fmaf(sv.x, u0.x, fmaf(sv.y, u1.x, fmaf(sv.z, u2.x, fmaf(sv.w, u3.x, C[s].x))));
          C[s].y = fmaf(sv.x, u0.y, fmaf(sv.y, u1.y, fmaf(sv.z, u2.y, fmaf(sv.w, u3.y, C[s].y))));
          C[s].z = fmaf(sv.x, u0.z, fmaf(sv.y, u1.z, fmaf(sv.z, u2.z, fmaf(sv.w, u3.z, C[s].z))));
          C[s].w = fmaf(sv.x, u0.w, fmaf(sv.y, u1.w, fmaf(sv.z, u2.w, fmaf(sv.w, u3.w, C[s].w))));
        }
      }
      // k-split reduction across q (lane bits 0..2) — tree identical to rec3
#pragma unroll
      for (int off = 1; off <= 4; off <<= 1) {
#pragma unroll
        for (int s = 0; s < 8; ++s) {
          C[s].x += __shfl_xor(C[s].x, off, 64);
          C[s].y += __shfl_xor(C[s].y, off, 64);
          C[s].z += __shfl_xor(C[s].z, off, 64);
          C[s].w += __shfl_xor(C[s].w, off, 64);
        }
      }
      cA = C[0];
#pragma unroll
      for (int s = 1; s < 8; ++s) {
        if (q == s) cA = C[s];
      }
    }

    // ---- matmul B ----
    float4 cB = make_float4(0.f, 0.f, 0.f, 0.f);
    if (dB) {
      float4 C[8];
#pragma unroll
      for (int s = 0; s < 8; ++s) C[s] = make_float4(0.f, 0.f, 0.f, 0.f);
#pragma unroll
      for (int k4 = 0; k4 < 8; ++k4) {
        const float4 u0 = u4[4 * k4 + 0], u1 = u4[4 * k4 + 1];
        const float4 u2 = u4[4 * k4 + 2], u3 = u4[4 * k4 + 3];
#pragma unroll
        for (int s = 0; s < 8; ++s) {
          float4 sv = *(const float4*)(SqB + s * kStRow + 4 * k4);
          C[s].x = fmaf(sv.x, u0.x, fmaf(sv.y, u1.x, fmaf(sv.z, u2.x, fmaf(sv.w, u3.x, C[s].x))));
          C[s].y = fmaf(sv.x, u0.y, fmaf(sv.y, u1.y, fmaf(sv.z, u2.y, fmaf(sv.w, u3.y, C[s].y))));
          C[s].z = fmaf(sv.x, u0.z, fmaf(sv.y, u1.z, fmaf(sv.z, u2.z, fmaf(sv.w, u3.z, C[s].z))));
          C[s].w = fmaf(sv.x, u0.w, fmaf(sv.y, u1.w, fmaf(sv.z, u2.w, fmaf(sv.w, u3.w, C[s].w))));
        }
      }
#pragma unroll
      for (int off = 1; off <= 4; off <<= 1) {
#pragma unroll
        for (int s = 0; s < 8; ++s) {
          C[s].x += __shfl_xor(C[s].x, off, 64);
          C[s].y += __shfl_xor(C[s].y, off, 64);
          C[s].z += __shfl_xor(C[s].z, off, 64);
          C[s].w += __shfl_xor(C[s].w, off, 64);
        }
      }
      cB = C[0];
#pragma unroll
      for (int s = 1; s < 8; ++s) {
        if (q == s) cB = C[s];
      }
    }

    __syncthreads();  // B1: redG* complete; all St* matmul reads done

    float4 hA, hB;
    if (dA) {
      float4 ra = *(const float4*)(redGA + q * kRedRow);
      float4 rb = *(const float4*)(redGA + q * kRedRow + 4);
      float gs = ((ra.x + ra.y) + (ra.z + ra.w)) + ((rb.x + rb.y) + (rb.z + rb.w)) + gkqA + gb;
      float gq = 1.f / (1.f + expf(-gs));
      float t0 = cA.x + kvq.x + xwA4.x; t0 = t0 > 0.f ? t0 : expm1f(t0);
      float t1 = cA.y + kvq.y + xwA4.y; t1 = t1 > 0.f ? t1 : expm1f(t1);
      float t2 = cA.z + kvq.z + xwA4.z; t2 = t2 > 0.f ? t2 : expm1f(t2);
      float t3 = cA.w + kvq.w + xwA4.w; t3 = t3 > 0.f ? t3 : expm1f(t3);
      hA.x = fmaf(gq, t0, srA.x);
      hA.y = fmaf(gq, t1, srA.y);
      hA.z = fmaf(gq, t2, srA.z);
      hA.w = fmaf(gq, t3, srA.w);
      float pn = fmaf(hA.x, hA.x, fmaf(hA.y, hA.y, fmaf(hA.z, hA.z, hA.w * hA.w)));
      pn += __shfl_xor(pn, 8, 64);
      pn += __shfl_xor(pn, 16, 64);
      pn += __shfl_xor(pn, 32, 64);
      if (lane < 8) redNA[lane * kRedRow + w] = pn;
    }
    if (dB) {
      float4 ra = *(const float4*)(redGB + q * kRedRow);
      float4 rb = *(const float4*)(redGB + q * kRedRow + 4);
      float gs = ((ra.x + ra.y) + (ra.z + ra.w)) + ((rb.x + rb.y) + (rb.z + rb.w)) + gkqB + gb;
      float gq = 1.f / (1.f + expf(-gs));
      float t0 = cB.x + kvq.x + xwB4.x; t0 = t0 > 0.f ? t0 : expm1f(t0);
      float t1 = cB.y + kvq.y + xwB4.y; t1 = t1 > 0.f ? t1 : expm1f(t1);
      float t2 = cB.z + kvq.z + xwB4.z; t2 = t2 > 0.f ? t2 : expm1f(t2);
      float t3 = cB.w + kvq.w + xwB4.w; t3 = t3 > 0.f ? t3 : expm1f(t3);
      hB.x = fmaf(gq, t0, srB.x);
      hB.y = fmaf(gq, t1, srB.y);
      hB.z = fmaf(gq, t2, srB.z);
      hB.w = fmaf(gq, t3, srB.w);
      float pn = fmaf(hB.x, hB.x, fmaf(hB.y, hB.y, fmaf(hB.z, hB.z, hB.w * hB.w)));
      pn += __shfl_xor(pn, 8, 64);
      pn += __shfl_xor(pn, 16, 64);
      pn += __shfl_xor(pn, 32, 64);
      if (lane < 8) redNB[lane * kRedRow + w] = pn;
    }
    __syncthreads();  // B2: redN* complete

    if (dA) {
      float4 na = *(const float4*)(redNA + q * kRedRow);
      float4 nb = *(const float4*)(redNA + q * kRedRow + 4);
      float ns = ((na.x + na.y) + (na.z + na.w)) + ((nb.x + nb.y) + (nb.z + nb.w));
      float inh = 1.f / fmaxf(sqrtf(ns), 1e-12f);
      srA.x = hA.x * inh; srA.y = hA.y * inh; srA.z = hA.z * inh; srA.w = hA.w * inh;
      *(float4*)(StA + q * kStRow + c0p) = srA;
    }
    if (dB) {
      float4 na = *(const float4*)(redNB + q * kRedRow);
      float4 nb = *(const float4*)(redNB + q * kRedRow + 4);
      float ns = ((na.x + na.y) + (na.z + na.w)) + ((nb.x + nb.y) + (nb.z + nb.w));
      float inh = 1.f / fmaxf(sqrtf(ns), 1e-12f);
      srB.x = hB.x * inh; srB.y = hB.y * inh; srB.z = hB.z * inh; srB.w = hB.w * inh;
      *(float4*)(StB + q * kStRow + c0p) = srB;
    }
    __syncthreads();  // B3: new states visible for next step
  }

  // final states -> out
  for (int i = tid; i < kS * kD; i += 512) {
    int s = i >> 8, dd = i & 255;
    int pa = s * kStRow + physk(dd);
    out[(size_t)bA * kS * kD + i] = StA[pa];
    out[(size_t)bB * kS * kD + i] = StB[pa];
  }
}

extern "C" void kernel_launch(void* const* d_in, const int* in_sizes, int n_in,
                              void* d_out, int out_size, void* d_ws, size_t ws_size,
                              hipStream_t stream) {
  const float* inputs     = (const float*)d_in[0];
  const int*   lengths    = (const int*)  d_in[1];
  const float* keys       = (const float*)d_in[2];
  const float* U          = (const float*)d_in[3];
  const float* V          = (const float*)d_in[4];
  const float* W          = (const float*)d_in[5];
  const float* gate_bias  = (const float*)d_in[6];
  const float* state_bias = (const float*)d_in[7];

  const size_t xw_elems = (size_t)kB * kT * kD;
  const size_t gk_elems = (size_t)kB * kT * kS;
  float* XW = (float*)d_ws;
  float* GK = (float*)d_ws + xw_elems;
  int*   order = (int*)((float*)d_ws + xw_elems + gk_elems);

  sort_lengths_kernel<<<dim3(1), dim3(512), 0, stream>>>(lengths, order);
  xw_gemm_kernel<<<dim3((kB * kT) / 32), dim3(256), 0, stream>>>(inputs, W, lengths, XW);
  gk_kernel<<<dim3(kB), dim3(256), 0, stream>>>(inputs, keys, lengths, GK);
  dynmem_rec4_kernel<<<dim3(kB / 2), dim3(512), 0, stream>>>(
      inputs, lengths, keys, U, V, gate_bias, state_bias, XW, GK, order, (float*)d_out);
}